// Round 11
// baseline (573.904 us; speedup 1.0000x reference)
//
#include <hip/hip_runtime.h>
#include <hip/hip_bf16.h>
#include <stdint.h>

// Transformer block: B=8, T=2048, C=1024, fp32 in/out, bf16 MFMA internally.
// Round 11: m97-style GEMM for everything — 128x128 tile, BK=64, 4 waves,
// SINGLE-buffered 32 KiB LDS (=> ~3 blocks/CU, m114 implicit cross-block
// overlap), 128B LDS rows with full 3-bit XOR swizzle (bank-conflict free),
// unpinned 2-barrier K-loop, global_load_lds width-16 staging, XCD remap.
// Plus: fused QKV epilogue (h read once) and bf16 x_mid residual path
// (proj writes bf16; rmsnorm2/FFN2 read bf16) to cut fp32 traffic.

#define C_DIM 1024
#define T_DIM 2048
#define B_DIM 8

typedef float f32x4 __attribute__((ext_vector_type(4)));
typedef __bf16 bf16x8 __attribute__((ext_vector_type(8)));

typedef const __attribute__((address_space(1))) void gvoid_t;
typedef __attribute__((address_space(3))) void lvoid_t;

__device__ __forceinline__ void gload_lds16(const void* g, void* l) {
    __builtin_amdgcn_global_load_lds((gvoid_t*)g, (lvoid_t*)l, 16, 0, 0);
}

__device__ __forceinline__ unsigned short f2bf_bits(float f) {
    __hip_bfloat16 h = __float2bfloat16(f);
    return *reinterpret_cast<unsigned short*>(&h);
}

// Bijective XCD-chunked remap (m204)
__device__ __forceinline__ void xcd_remap(int& bx, int& by, int& bz) {
    const int gx = gridDim.x, gy = gridDim.y;
    const int nwg = gx * gy * (int)gridDim.z;
    const int orig = bx + gx * (by + gy * bz);
    const int q = nwg >> 3, r = nwg & 7;
    const int xcd = orig & 7, pos = orig >> 3;
    const int neu = (xcd < r ? xcd * (q + 1) : r * (q + 1) + (xcd - r) * q) + pos;
    bx = neu % gx;
    const int t = neu / gx;
    by = t % gy;
    bz = t / gy;
}

// ---------------------------------------------------------------------------
// 128x128 GEMM, BK=64, 4 waves (2Mx2N), single-buffered LDS (A 16KB + B 16KB).
// Staging: wave w covers rows [32w,32w+32) of the tile; 4 gload_lds16 insts
// each move 1KB (8 rows x 128B); lane l -> row 8i+(l>>3), LDS slot l&7 holds
// global 16B-chunk (l&7)^(l>>3)  [involution: LDS(r,s) = G(r, s^(r&7))].
// Read: chunk c of row r at LDS slot c^(r&7); r&7 == l15&7 for all frags ->
// banks spread 8-wide, 2 lanes/bank (free, m136).
// EPI: 0 bf16; 3 bf16 silu; 4 bf16*scale;
//      6 fused qkv route (Cout=q, C2=k, C3=vT[B][C][T]);
//      8 x_mid = R(fp32) + acc -> bf16;  9 out = Rb(bf16) + acc -> fp32.
// CMODE: 0 none; 1 causal block skip; 2 causal K clip (kmax = m0+128).
// ---------------------------------------------------------------------------
template<int EPI, int CMODE>
__global__ __launch_bounds__(256)
void gemm128(const __hip_bfloat16* A, const __hip_bfloat16* Bt,
             void* Cout, const void* Rv, void* C2, void* C3,
             int K, int lda, int ldb, int ldc,
             long long sA, long long sB, long long sC, float scale)
{
    int bx = blockIdx.x, by = blockIdx.y, bz = blockIdx.z;
    xcd_remap(bx, by, bz);
    if constexpr (CMODE == 1) { if (bx > by) return; }

    const int tid  = threadIdx.x;
    const int lane = tid & 63, wave = tid >> 6;
    const int l15  = lane & 15, l4 = lane >> 4;
    const int wr   = wave >> 1, wc = wave & 1;
    const int m0   = by * 128, n0 = bx * 128;

    A  += (long long)bz * sA;
    Bt += (long long)bz * sB;

    __shared__ __align__(16) char lds_[32768];   // A [0,16K), B [16K,32K)

    int kmax = K;
    if constexpr (CMODE == 2) { int km = m0 + 128; kmax = km < K ? km : K; }
    const int NT = kmax >> 6;

    // staging addresses (per lane)
    const int sr = lane >> 3;                 // 0..7
    const int ss = (lane & 7) ^ sr;           // pre-swizzled global slot
    const __hip_bfloat16* Ag = A  + (long long)(m0 + 32 * wave + sr) * lda + ss * 8;
    const __hip_bfloat16* Bg = Bt + (long long)(n0 + 32 * wave + sr) * ldb + ss * 8;
    char* lAw = lds_ + wave * 4096;
    char* lBw = lds_ + 16384 + wave * 4096;

    // read-side offsets: byte = l15*128 + ((chunk ^ (l15&7))<<4), chunk = ks*4+l4
    const int offk0 = l15 * 128 + (((l4)     ^ (l15 & 7)) << 4);
    const int offk1 = l15 * 128 + (((4 + l4) ^ (l15 & 7)) << 4);

    f32x4 acc[4][4];
#pragma unroll
    for (int i = 0; i < 4; ++i)
#pragma unroll
        for (int j = 0; j < 4; ++j) acc[i][j] = (f32x4){0.f, 0.f, 0.f, 0.f};

    for (int t = 0; t < NT; ++t) {
        // stage tile t (8 x gload_lds16)
#pragma unroll
        for (int i = 0; i < 4; ++i) {
            gload_lds16(Ag + (long long)t * 64 + i * 8 * lda, lAw + i * 1024);
            gload_lds16(Bg + (long long)t * 64 + i * 8 * ldb, lBw + i * 1024);
        }
        asm volatile("s_waitcnt vmcnt(0)" ::: "memory");
        __builtin_amdgcn_s_barrier();

        bf16x8 aR[4][2], bR[4][2];
#pragma unroll
        for (int mf = 0; mf < 4; ++mf) {
            const char* p = lds_ + (wr * 64 + mf * 16) * 128;
            aR[mf][0] = *(const bf16x8*)(p + offk0);
            aR[mf][1] = *(const bf16x8*)(p + offk1);
        }
#pragma unroll
        for (int nf = 0; nf < 4; ++nf) {
            const char* p = lds_ + 16384 + (wc * 64 + nf * 16) * 128;
            bR[nf][0] = *(const bf16x8*)(p + offk0);
            bR[nf][1] = *(const bf16x8*)(p + offk1);
        }
        __builtin_amdgcn_s_setprio(1);
#pragma unroll
        for (int mf = 0; mf < 4; ++mf)
#pragma unroll
            for (int nf = 0; nf < 4; ++nf)
#pragma unroll
                for (int ks = 0; ks < 2; ++ks)
                    acc[mf][nf] = __builtin_amdgcn_mfma_f32_16x16x32_bf16(
                        aR[mf][ks], bR[nf][ks], acc[mf][nf], 0, 0, 0);
        __builtin_amdgcn_s_setprio(0);
        asm volatile("s_waitcnt lgkmcnt(0)" ::: "memory");
        __builtin_amdgcn_s_barrier();
    }

    // epilogue: row = m0 + wr*64 + mf*16 + l4*4 + r ; col = n0 + wc*64 + nf*16 + l15
    const long long cbase = (long long)bz * sC;
#pragma unroll
    for (int mf = 0; mf < 4; ++mf) {
        const int rbase = m0 + wr * 64 + mf * 16 + l4 * 4;
#pragma unroll
        for (int nf = 0; nf < 4; ++nf) {
            const int col = n0 + wc * 64 + nf * 16 + l15;
#pragma unroll
            for (int r = 0; r < 4; ++r) {
                const float v = acc[mf][nf][r];
                const int row = rbase + r;
                if constexpr (EPI == 6) {
                    const int seg = col >> 10, ncol = col & 1023;
                    if (seg == 0) {
                        ((__hip_bfloat16*)Cout)[(long long)row * 1024 + ncol] =
                            __float2bfloat16(v);
                    } else if (seg == 1) {
                        ((__hip_bfloat16*)C2)[(long long)row * 1024 + ncol] =
                            __float2bfloat16(v);
                    } else {
                        ((__hip_bfloat16*)C3)[((long long)(row >> 11) * C_DIM + ncol) * T_DIM
                                              + (row & 2047)] = __float2bfloat16(v);
                    }
                } else {
                    const long long idx = cbase + (long long)row * ldc + col;
                    if constexpr (EPI == 0) {
                        ((__hip_bfloat16*)Cout)[idx] = __float2bfloat16(v);
                    } else if constexpr (EPI == 3) {
                        const float s = v / (1.f + __expf(-v));
                        ((__hip_bfloat16*)Cout)[idx] = __float2bfloat16(s);
                    } else if constexpr (EPI == 4) {
                        ((__hip_bfloat16*)Cout)[idx] = __float2bfloat16(v * scale);
                    } else if constexpr (EPI == 8) {
                        const float xr = ((const float*)Rv)[idx];
                        ((__hip_bfloat16*)Cout)[idx] = __float2bfloat16(v + xr);
                    } else { // EPI == 9
                        const float xr =
                            __bfloat162float(((const __hip_bfloat16*)Rv)[idx]);
                        ((float*)Cout)[idx] = v + xr;
                    }
                }
            }
        }
    }
}

// ---------------------------------------------------------------------------
// RMSNorm: one block per row of C_DIM; input fp32 or bf16, output bf16.
// ---------------------------------------------------------------------------
template<bool BF16IN>
__global__ __launch_bounds__(256)
void rmsnorm_kernel(const void* __restrict__ xin, const float* __restrict__ g,
                    __hip_bfloat16* __restrict__ out)
{
    const long long row = blockIdx.x;
    const int tid = threadIdx.x;
    float e0, e1, e2, e3;
    if constexpr (BF16IN) {
        const ushort4 u = ((const ushort4*)((const __hip_bfloat16*)xin + row * C_DIM))[tid];
        e0 = __uint_as_float((unsigned)u.x << 16);
        e1 = __uint_as_float((unsigned)u.y << 16);
        e2 = __uint_as_float((unsigned)u.z << 16);
        e3 = __uint_as_float((unsigned)u.w << 16);
    } else {
        const float4 v = ((const float4*)((const float*)xin + row * C_DIM))[tid];
        e0 = v.x; e1 = v.y; e2 = v.z; e3 = v.w;
    }
    float ss = e0 * e0 + e1 * e1 + e2 * e2 + e3 * e3;
#pragma unroll
    for (int off = 32; off; off >>= 1) ss += __shfl_xor(ss, off);
    __shared__ float red[4];
    if ((tid & 63) == 0) red[tid >> 6] = ss;
    __syncthreads();
    ss = red[0] + red[1] + red[2] + red[3];
    const float sc = rsqrtf(ss * (1.0f / C_DIM) + 1e-6f);
    const float4 gv = ((const float4*)g)[tid];
    ushort4 u;
    u.x = f2bf_bits(e0 * sc * gv.x);
    u.y = f2bf_bits(e1 * sc * gv.y);
    u.z = f2bf_bits(e2 * sc * gv.z);
    u.w = f2bf_bits(e3 * sc * gv.w);
    *(ushort4*)(out + row * C_DIM + tid * 4) = u;
}

// ---------------------------------------------------------------------------
// Causal softmax, IN PLACE on bf16 S [B,T,T] -> P bf16 (zeros above diagonal).
// ---------------------------------------------------------------------------
__global__ __launch_bounds__(256)
void softmax_causal(__hip_bfloat16* __restrict__ SP)
{
    const int i = blockIdx.x, b = blockIdx.y;
    __hip_bfloat16* row = SP + ((long long)b * T_DIM + i) * T_DIM;
    const int tid = threadIdx.x;
    const int jbase = tid * 8;

    uint4 raw = ((const uint4*)row)[tid];
    float v[8];
    const unsigned w[4] = {raw.x, raw.y, raw.z, raw.w};
#pragma unroll
    for (int c = 0; c < 4; ++c) {
        unsigned lo = w[c] << 16;
        unsigned hi = w[c] & 0xFFFF0000u;
        v[2 * c]     = __uint_as_float(lo);
        v[2 * c + 1] = __uint_as_float(hi);
    }
#pragma unroll
    for (int e = 0; e < 8; ++e)
        if (jbase + e > i) v[e] = -1e30f;

    float m = v[0];
#pragma unroll
    for (int e = 1; e < 8; ++e) m = fmaxf(m, v[e]);
#pragma unroll
    for (int off = 32; off; off >>= 1) m = fmaxf(m, __shfl_xor(m, off));
    __shared__ float redm[4], reds[4];
    if ((tid & 63) == 0) redm[tid >> 6] = m;
    __syncthreads();
    m = fmaxf(fmaxf(redm[0], redm[1]), fmaxf(redm[2], redm[3]));

    float e8[8];
    float s = 0.f;
#pragma unroll
    for (int e = 0; e < 8; ++e) { e8[e] = __expf(v[e] - m); s += e8[e]; }
#pragma unroll
    for (int off = 32; off; off >>= 1) s += __shfl_xor(s, off);
    if ((tid & 63) == 0) reds[tid >> 6] = s;
    __syncthreads();
    s = reds[0] + reds[1] + reds[2] + reds[3];
    const float inv = 1.f / s;

    uint4 outw;
    unsigned o[4];
#pragma unroll
    for (int c = 0; c < 4; ++c) {
        unsigned lo = f2bf_bits(e8[2 * c] * inv);
        unsigned hi = f2bf_bits(e8[2 * c + 1] * inv);
        o[c] = lo | (hi << 16);
    }
    outw.x = o[0]; outw.y = o[1]; outw.z = o[2]; outw.w = o[3];
    ((uint4*)row)[tid] = outw;
}

// ---------------------------------------------------------------------------
// Weight cast + transpose: in fp32 [K,N] -> out bf16 [N,K]
// ---------------------------------------------------------------------------
__global__ __launch_bounds__(256)
void wcast_t(const float* __restrict__ in, __hip_bfloat16* __restrict__ out,
             int K, int N)
{
    __shared__ float t[32][33];
    const int n0 = blockIdx.x * 32, k0 = blockIdx.y * 32;
    const int tx = threadIdx.x, ty = threadIdx.y;
#pragma unroll
    for (int r = ty; r < 32; r += 8)
        t[r][tx] = in[(long long)(k0 + r) * N + n0 + tx];
    __syncthreads();
#pragma unroll
    for (int r = ty; r < 32; r += 8)
        out[(long long)(n0 + r) * K + k0 + tx] = __float2bfloat16(t[tx][r]);
}

// ---------------------------------------------------------------------------
extern "C" void kernel_launch(void* const* d_in, const int* in_sizes, int n_in,
                              void* d_out, int out_size, void* d_ws, size_t ws_size,
                              hipStream_t stream)
{
    const float* x      = (const float*)d_in[0];
    const float* w_qkv  = (const float*)d_in[1];
    const float* w_proj = (const float*)d_in[2];
    const float* w1     = (const float*)d_in[3];
    const float* w2     = (const float*)d_in[4];
    const float* g1     = (const float*)d_in[5];
    const float* g2     = (const float*)d_in[6];
    float* out = (float*)d_out;
    char* ws = (char*)d_ws;

    const size_t SP_off = 0;                       // S/P bf16 [8,2048,2048] 64MiB
    const size_t h_off  = 0;                       // h bf16 (before S exists)
    const size_t u_off  = 0;                       // u bf16 (after P dead)
    const size_t q_off  = 67108864ull;             // q bf16 -> h2
    const size_t k_off  = 100663296ull;            // k bf16 -> av
    const size_t vT_off = 134217728ull;            // vT bf16 -> x_mid bf16 (after AV)
    const size_t wq_off = 167772160ull;            // 6.29MB
    const size_t wp_off = wq_off + 6291456ull;     // 2.10MB
    const size_t w1_off = wp_off + 2097152ull;     // 4.19MB
    const size_t w2_off = w1_off + 4194304ull;     // 4.19MB
    const size_t NEED   = w2_off + 4194304ull;     // 176 MiB

    if (ws_size < NEED) return;  // guard: fail absmax instead of faulting

    auto bf = [&](size_t off) { return (__hip_bfloat16*)(ws + off); };

    // 1. weights -> bf16 [N,K]
    wcast_t<<<dim3(96, 32), dim3(32, 8), 0, stream>>>(w_qkv,  bf(wq_off), 1024, 3072);
    wcast_t<<<dim3(32, 32), dim3(32, 8), 0, stream>>>(w_proj, bf(wp_off), 1024, 1024);
    wcast_t<<<dim3(64, 32), dim3(32, 8), 0, stream>>>(w1,     bf(w1_off), 1024, 2048);
    wcast_t<<<dim3(32, 64), dim3(32, 8), 0, stream>>>(w2,     bf(w2_off), 2048, 1024);

    // 2. h = rmsnorm(x, g1)
    rmsnorm_kernel<false><<<16384, 256, 0, stream>>>(x, g1, bf(h_off));

    // 3. fused qkv: q, k, vT = (h @ Wv)^T in one dispatch (h read once)
    gemm128<6, 0><<<dim3(24, 128, 1), 256, 0, stream>>>(
        bf(h_off), bf(wq_off), bf(q_off), nullptr, bf(k_off), bf(vT_off),
        1024, 1024, 1024, 1024, 0, 0, 0, 1.f);

    // 4. S = q @ k^T * 1/32  (causal block skip at 128 granularity)
    gemm128<4, 1><<<dim3(16, 16, 8), 256, 0, stream>>>(
        bf(q_off), bf(k_off), bf(SP_off), nullptr, nullptr, nullptr,
        1024, 1024, 1024, 2048,
        (long long)T_DIM * C_DIM, (long long)T_DIM * C_DIM, (long long)T_DIM * T_DIM,
        0.03125f);

    // 5. P = causal softmax(S), in place
    softmax_causal<<<dim3(2048, 8), 256, 0, stream>>>(bf(SP_off));

    // 6. av = P @ V  (vT as Bt, K clipped at diagonal)
    gemm128<0, 2><<<dim3(8, 16, 8), 256, 0, stream>>>(
        bf(SP_off), bf(vT_off), bf(k_off) /*av*/, nullptr, nullptr, nullptr,
        2048, 2048, 2048, 1024,
        (long long)T_DIM * T_DIM, (long long)C_DIM * T_DIM, (long long)T_DIM * C_DIM,
        1.f);

    // 7. x_mid(bf16) = x(fp32) + av @ w_proj   (-> vT region, vT dead)
    gemm128<8, 0><<<dim3(8, 128, 1), 256, 0, stream>>>(
        bf(k_off) /*av*/, bf(wp_off), bf(vT_off) /*x_mid*/, x, nullptr, nullptr,
        1024, 1024, 1024, 1024, 0, 0, 0, 1.f);

    // 8. h2 = rmsnorm(x_mid bf16, g2)   (-> q region)
    rmsnorm_kernel<true><<<16384, 256, 0, stream>>>(bf(vT_off), g2, bf(q_off));

    // 9. u = silu(h2 @ w1)   (-> SP region, dead)
    gemm128<3, 0><<<dim3(16, 128, 1), 256, 0, stream>>>(
        bf(q_off), bf(w1_off), bf(u_off), nullptr, nullptr, nullptr,
        1024, 1024, 1024, 2048, 0, 0, 0, 1.f);

    // 10. out(fp32) = x_mid(bf16) + u @ w2
    gemm128<9, 0><<<dim3(8, 128, 1), 256, 0, stream>>>(
        bf(u_off), bf(w2_off), out, bf(vT_off) /*x_mid*/, nullptr, nullptr,
        2048, 2048, 2048, 1024, 0, 0, 0, 1.f);
}